// Round 1
// baseline (1132.679 us; speedup 1.0000x reference)
//
#include <hip/hip_runtime.h>
#include <math.h>

// ---------------------------------------------------------------------------
// SplineConv GNN: 3 layers (in=2->16, 16->16, 16->16), K=5 per dim (dim=2),
// degree-1 open B-spline, mean aggregation, root weight + bias, ReLU.
// Final: FC [16,1] + bias + sigmoid -> out[N] f32.
// ---------------------------------------------------------------------------

#define KS 5  // kernel size per pseudo dim

// ---- degree count -----------------------------------------------------------
__global__ void deg_count_kernel(const int* __restrict__ dst, float* __restrict__ deg, int E) {
    int stride = gridDim.x * blockDim.x;
    for (int e = blockIdx.x * blockDim.x + threadIdx.x; e < E; e += stride) {
        atomicAdd(&deg[dst[e]], 1.0f);
    }
}

__global__ void deg_inv_kernel(float* __restrict__ deg, int N) {
    int i = blockIdx.x * blockDim.x + threadIdx.x;
    if (i < N) deg[i] = 1.0f / fmaxf(deg[i], 1.0f);
}

// ---- edge message + scatter-add --------------------------------------------
// One thread per (edge, out-channel). 16 threads per edge.
template <int IN>
__global__ void edge_kernel(const float* __restrict__ h,     // [N, IN]
                            const int* __restrict__ src,
                            const int* __restrict__ dst,
                            const float* __restrict__ eattr,  // [E, 2]
                            const float* __restrict__ W,      // [25, IN, 16]
                            float* __restrict__ agg,          // [N, 16] (zeroed)
                            int E) {
    __shared__ float Wl[25 * IN * 16];
    for (int i = threadIdx.x; i < 25 * IN * 16; i += blockDim.x) Wl[i] = W[i];
    __syncthreads();

    int t = blockIdx.x * blockDim.x + threadIdx.x;
    int e = t >> 4;
    if (e >= E) return;
    int o = t & 15;

    float a0 = eattr[2 * e + 0] * (float)(KS - 1);
    float a1 = eattr[2 * e + 1] * (float)(KS - 1);
    float k0 = fminf(fmaxf(floorf(a0), 0.0f), (float)(KS - 2));
    float k1 = fminf(fmaxf(floorf(a1), 0.0f), (float)(KS - 2));
    float f0 = a0 - k0;
    float f1 = a1 - k1;
    int i0 = (int)k0;
    int i1 = (int)k1;
    float b0[2] = {1.0f - f0, f0};
    float b1[2] = {1.0f - f1, f1};

    int s = src[e];
    float hv[IN];
    if (IN == 16) {
        const float4* h4 = reinterpret_cast<const float4*>(h + (size_t)s * IN);
        #pragma unroll
        for (int q = 0; q < IN / 4; ++q) {
            float4 v = h4[q];
            hv[4 * q + 0] = v.x; hv[4 * q + 1] = v.y;
            hv[4 * q + 2] = v.z; hv[4 * q + 3] = v.w;
        }
    } else {
        #pragma unroll
        for (int i = 0; i < IN; ++i) hv[i] = h[(size_t)s * IN + i];
    }

    float acc = 0.0f;
    #pragma unroll
    for (int s1 = 0; s1 < 2; ++s1) {
        #pragma unroll
        for (int s0 = 0; s0 < 2; ++s0) {
            float bb = b0[s0] * b1[s1];
            int wi = (i0 + s0) + KS * (i1 + s1);
            const float* wp = &Wl[(wi * IN) * 16 + o];
            float p = 0.0f;
            #pragma unroll
            for (int i = 0; i < IN; ++i) p += hv[i] * wp[i * 16];
            acc += bb * p;
        }
    }
    atomicAdd(&agg[(size_t)dst[e] * 16 + o], acc);
}

// ---- finalize: out = relu(agg * invdeg + hin @ root + bias) ----------------
template <int IN>
__global__ void finalize_kernel(const float* __restrict__ hin,    // [N, IN]
                                const float* __restrict__ root,   // [IN, 16]
                                const float* __restrict__ bias,   // [16]
                                const float* __restrict__ invdeg, // [N]
                                float* __restrict__ h,            // [N,16] in: agg / out: act
                                int N) {
    int t = blockIdx.x * blockDim.x + threadIdx.x;
    if (t >= N * 16) return;
    int o = t & 15;
    int n = t >> 4;
    float acc = h[t] * invdeg[n];
    #pragma unroll
    for (int i = 0; i < IN; ++i) acc += hin[(size_t)n * IN + i] * root[i * 16 + o];
    acc += bias[o];
    h[t] = fmaxf(acc, 0.0f);
}

// ---- final FC + sigmoid ----------------------------------------------------
__global__ void fc_kernel(const float* __restrict__ h,   // [N,16]
                          const float* __restrict__ fcw, // [16]
                          const float* __restrict__ fcb, // [1]
                          float* __restrict__ out, int N) {
    int n = blockIdx.x * blockDim.x + threadIdx.x;
    if (n >= N) return;
    const float4* h4 = reinterpret_cast<const float4*>(h + (size_t)n * 16);
    float acc = fcb[0];
    #pragma unroll
    for (int q = 0; q < 4; ++q) {
        float4 v = h4[q];
        acc += v.x * fcw[4 * q + 0] + v.y * fcw[4 * q + 1] +
               v.z * fcw[4 * q + 2] + v.w * fcw[4 * q + 3];
    }
    out[n] = 1.0f / (1.0f + expf(-acc));
}

extern "C" void kernel_launch(void* const* d_in, const int* in_sizes, int n_in,
                              void* d_out, int out_size, void* d_ws, size_t ws_size,
                              hipStream_t stream) {
    const float* x      = (const float*)d_in[0];   // [N,2]
    const int*   eidx   = (const int*)d_in[1];     // [2,E]
    const float* eattr  = (const float*)d_in[2];   // [E,2]
    const float* W1     = (const float*)d_in[3];
    const float* root1  = (const float*)d_in[4];
    const float* b1     = (const float*)d_in[5];
    const float* W2     = (const float*)d_in[6];
    const float* root2  = (const float*)d_in[7];
    const float* b2     = (const float*)d_in[8];
    const float* W3     = (const float*)d_in[9];
    const float* root3  = (const float*)d_in[10];
    const float* b3     = (const float*)d_in[11];
    const float* fcw    = (const float*)d_in[12];
    const float* fcb    = (const float*)d_in[13];
    float* out = (float*)d_out;

    const int N = in_sizes[0] / 2;
    const int E = in_sizes[2] / 2;
    const int* src = eidx;
    const int* dst = eidx + E;

    float* hA  = (float*)d_ws;            // [N,16]
    float* hB  = hA + (size_t)N * 16;     // [N,16]
    float* deg = hB + (size_t)N * 16;     // [N]

    const int BT = 256;
    const int edge_grid = (E * 16 + BT - 1) / BT;
    const int node_grid = (N * 16 + BT - 1) / BT;

    // degree (shared by all layers)
    hipMemsetAsync(deg, 0, (size_t)N * sizeof(float), stream);
    deg_count_kernel<<<2048, BT, 0, stream>>>(dst, deg, E);
    deg_inv_kernel<<<(N + BT - 1) / BT, BT, 0, stream>>>(deg, N);

    // layer 1: x[N,2] -> hA
    hipMemsetAsync(hA, 0, (size_t)N * 16 * sizeof(float), stream);
    edge_kernel<2><<<edge_grid, BT, 0, stream>>>(x, src, dst, eattr, W1, hA, E);
    finalize_kernel<2><<<node_grid, BT, 0, stream>>>(x, root1, b1, deg, hA, N);

    // layer 2: hA -> hB
    hipMemsetAsync(hB, 0, (size_t)N * 16 * sizeof(float), stream);
    edge_kernel<16><<<edge_grid, BT, 0, stream>>>(hA, src, dst, eattr, W2, hB, E);
    finalize_kernel<16><<<node_grid, BT, 0, stream>>>(hA, root2, b2, deg, hB, N);

    // layer 3: hB -> hA
    hipMemsetAsync(hA, 0, (size_t)N * 16 * sizeof(float), stream);
    edge_kernel<16><<<edge_grid, BT, 0, stream>>>(hB, src, dst, eattr, W3, hA, E);
    finalize_kernel<16><<<node_grid, BT, 0, stream>>>(hB, root3, b3, deg, hA, N);

    // final FC + sigmoid
    fc_kernel<<<(N + BT - 1) / BT, BT, 0, stream>>>(hA, fcw, fcb, out, N);
}